// Round 1
// baseline (772.158 us; speedup 1.0000x reference)
//
#include <hip/hip_runtime.h>
#include <cstdint>

// BinaryMLP fused forward for MI355X (gfx950) — register-resident redesign.
// h1 = relu(x @ sign(W1)^T + b1); h2 = relu(h1 @ sign(W2)^T + b2);
// h3 = relu(h2 @ sign(W3)^T + b3); out = h3 @ W4^T + b4
// B=524288, D_IN=196 (pad 224), H=128, D_OUT=10 (pad 16).
//
// Strategy: swapped-operand MFMA (A = weights, B = batch^T) so each lane's
// D column is its own batch row -> h stays lane-local through all layers.
// A k-permutation pi baked into the prepped W2/W3/W4 makes the MFMA D layout
// equal the next layer's B-fragment layout after a pure in-register
// relu + v_cvt_pk_bf16_f32. No LDS, no barriers, no shuffles; waves fully
// independent (32 batch rows each). x read directly global->reg as bf16.

typedef __attribute__((ext_vector_type(8))) short bf16x8;   // 8 bf16 (4 VGPRs)
typedef __attribute__((ext_vector_type(4))) float f32x4;    // MFMA accumulator

typedef unsigned short u16;
typedef unsigned int u32;

// ws element offsets (bf16 units)
#define WS_W1 0        // [128][224]  straight, zero-padded k>=196
#define WS_W2 28672    // [128][128]  pi-permuted columns
#define WS_W3 45056    // [128][128]  pi-permuted columns
#define WS_W4 61440    // [16][128]   pi-permuted, rows 10..15 zero
#define WS_TOTAL 63488 // 126976 bytes

__device__ __forceinline__ u32 bf16_rne(float x) {
  u32 u = __float_as_uint(x);
  return (u + 0x7FFFu + ((u >> 16) & 1u)) >> 16;
}

__device__ __forceinline__ u16 sign_bf16(float v) {
  return (v > 0.f) ? 0x3F80u : ((v < 0.f) ? 0xBF80u : 0u);
}

// pi: physical position pos -> logical k, chosen so that the previous layer's
// D layout (lane holds n = 16*mt + 4*q + jr) supplies position pos = 32*ks +
// 8*q + j with mt = 2*ks + (j>>2), jr = j&3 -- i.e. purely lane-local.
__device__ __forceinline__ int kperm(int pos) {
  return 32 * (pos >> 5) + 16 * ((pos >> 2) & 1) + 4 * ((pos >> 3) & 3) + (pos & 3);
}

__global__ __launch_bounds__(256) void prep_kernel(
    const float* __restrict__ W1, const float* __restrict__ W2,
    const float* __restrict__ W3, const float* __restrict__ W4,
    u16* __restrict__ ws) {
  int idx = blockIdx.x * 256 + threadIdx.x;   // grid 248 -> 63488 threads exact
  if (idx < WS_W2) {
    int n = idx / 224, k = idx - n * 224;
    ws[idx] = (k < 196) ? sign_bf16(W1[n * 196 + k]) : (u16)0;
  } else if (idx < WS_W3) {
    int j = idx - WS_W2; int n = j >> 7, p = j & 127;
    ws[idx] = sign_bf16(W2[(n << 7) + kperm(p)]);
  } else if (idx < WS_W4) {
    int j = idx - WS_W3; int n = j >> 7, p = j & 127;
    ws[idx] = sign_bf16(W3[(n << 7) + kperm(p)]);
  } else if (idx < WS_TOTAL) {
    int j = idx - WS_W4; int c = j >> 7, p = j & 127;
    ws[idx] = (c < 10) ? (u16)bf16_rne(W4[(c << 7) + kperm(p)]) : (u16)0;
  }
}

union BFU { bf16x8 v; u32 w[4]; };

__device__ __forceinline__ u32 cvtpk(float lo, float hi) {
  u32 r;
  asm("v_cvt_pk_bf16_f32 %0, %1, %2" : "=v"(r) : "v"(lo), "v"(hi));
  return r;
}
__device__ __forceinline__ u32 cvtpk_relu(float lo, float hi) {
  return cvtpk(fmaxf(lo, 0.f), fmaxf(hi, 0.f));
}

// acc tiles (8 per batch sub-tile) -> next layer's 4 B-fragments.
// frag[ks] = pairwise cvt_pk of relu(acc[2ks]) then relu(acc[2ks+1]).
__device__ __forceinline__ void to_bfrag(const f32x4 acc[8], bf16x8 bf[4]) {
#pragma unroll
  for (int ks = 0; ks < 4; ++ks) {
    BFU t;
    t.w[0] = cvtpk_relu(acc[2 * ks][0], acc[2 * ks][1]);
    t.w[1] = cvtpk_relu(acc[2 * ks][2], acc[2 * ks][3]);
    t.w[2] = cvtpk_relu(acc[2 * ks + 1][0], acc[2 * ks + 1][1]);
    t.w[3] = cvtpk_relu(acc[2 * ks + 1][2], acc[2 * ks + 1][3]);
    bf[ks] = t.v;
  }
}

// One K=128 hidden layer in orientation B: acc[mt] = bias; acc += Wp * h^T.
__device__ __forceinline__ void layer128(const u16* __restrict__ wp,
                                         const float* __restrict__ bias,
                                         int m, int q,
                                         const bf16x8 bf0[4], const bf16x8 bf1[4],
                                         f32x4 acc0[8], f32x4 acc1[8]) {
#pragma unroll
  for (int mt = 0; mt < 8; ++mt) {
    f32x4 bv = *(const f32x4*)(bias + mt * 16 + q * 4);
    acc0[mt] = bv;
    acc1[mt] = bv;
  }
  const u16* wb = wp + m * 128 + q * 8;
#pragma unroll
  for (int ks = 0; ks < 4; ++ks) {
#pragma unroll
    for (int mt = 0; mt < 8; ++mt) {
      bf16x8 a = *(const bf16x8*)(wb + mt * (16 * 128) + ks * 32);
      acc0[mt] = __builtin_amdgcn_mfma_f32_16x16x32_bf16(a, bf0[ks], acc0[mt], 0, 0, 0);
      acc1[mt] = __builtin_amdgcn_mfma_f32_16x16x32_bf16(a, bf1[ks], acc1[mt], 0, 0, 0);
    }
  }
}

__global__ __launch_bounds__(256, 3) void mlp_kernel(
    const float* __restrict__ x, const u16* __restrict__ ws,
    const float* __restrict__ b1, const float* __restrict__ b2,
    const float* __restrict__ b3, const float* __restrict__ b4,
    float* __restrict__ out) {
  const int tid = threadIdx.x;
  const int lane = tid & 63;
  const int wave = tid >> 6;
  const int m = lane & 15;   // A row index / B col (batch row) within 16
  const int q = lane >> 4;   // k-group: k = 32*ks + 8*q + j
  const size_t row0 = ((size_t)blockIdx.x * 4 + wave) * 32;  // 32 rows per wave

  f32x4 acc0[8], acc1[8];

  // ---- Layer 1: h1^T = W1 * x^T, K = 224 (7 k-steps), bias via acc init ----
#pragma unroll
  for (int mt = 0; mt < 8; ++mt) {
    f32x4 bv = *(const f32x4*)(b1 + mt * 16 + q * 4);
    acc0[mt] = bv;
    acc1[mt] = bv;
  }
  {
    const float* xr0 = x + (row0 + (size_t)m) * 196;  // batch sub-tile 0
    const float* xr1 = xr0 + 16 * 196;                // batch sub-tile 1
    const u16* w1 = ws + WS_W1 + m * 224 + q * 8;
#pragma unroll
    for (int ks = 0; ks < 7; ++ks) {
      BFU xf0, xf1;
      if (ks < 6) {
        float4 a0 = *(const float4*)(xr0 + ks * 32 + q * 8);
        float4 a1 = *(const float4*)(xr0 + ks * 32 + q * 8 + 4);
        float4 c0 = *(const float4*)(xr1 + ks * 32 + q * 8);
        float4 c1 = *(const float4*)(xr1 + ks * 32 + q * 8 + 4);
        xf0.w[0] = cvtpk(a0.x, a0.y); xf0.w[1] = cvtpk(a0.z, a0.w);
        xf0.w[2] = cvtpk(a1.x, a1.y); xf0.w[3] = cvtpk(a1.z, a1.w);
        xf1.w[0] = cvtpk(c0.x, c0.y); xf1.w[1] = cvtpk(c0.z, c0.w);
        xf1.w[2] = cvtpk(c1.x, c1.y); xf1.w[3] = cvtpk(c1.z, c1.w);
      } else {
        // tail: k = 192..223, only k in [192,196) valid (q==0, j<4)
        float4 a0 = make_float4(0.f, 0.f, 0.f, 0.f);
        float4 c0 = a0;
        if (q == 0) {
          a0 = *(const float4*)(xr0 + 192);
          c0 = *(const float4*)(xr1 + 192);
        }
        xf0.w[0] = cvtpk(a0.x, a0.y); xf0.w[1] = cvtpk(a0.z, a0.w);
        xf0.w[2] = 0u; xf0.w[3] = 0u;
        xf1.w[0] = cvtpk(c0.x, c0.y); xf1.w[1] = cvtpk(c0.z, c0.w);
        xf1.w[2] = 0u; xf1.w[3] = 0u;
      }
#pragma unroll
      for (int mt = 0; mt < 8; ++mt) {
        bf16x8 a = *(const bf16x8*)(w1 + mt * (16 * 224) + ks * 32);
        acc0[mt] = __builtin_amdgcn_mfma_f32_16x16x32_bf16(a, xf0.v, acc0[mt], 0, 0, 0);
        acc1[mt] = __builtin_amdgcn_mfma_f32_16x16x32_bf16(a, xf1.v, acc1[mt], 0, 0, 0);
      }
    }
  }

  bf16x8 bf0[4], bf1[4];
  to_bfrag(acc0, bf0);
  to_bfrag(acc1, bf1);
  layer128(ws + WS_W2, b2, m, q, bf0, bf1, acc0, acc1);
  to_bfrag(acc0, bf0);
  to_bfrag(acc1, bf1);
  layer128(ws + WS_W3, b3, m, q, bf0, bf1, acc0, acc1);
  to_bfrag(acc0, bf0);
  to_bfrag(acc1, bf1);

  // ---- Layer 4: out^T = W4p * h3^T (W4p rows 10..15 zero), no relu ----
  f32x4 o0, o1;
  {
    float bvv[4];
#pragma unroll
    for (int jr = 0; jr < 4; ++jr) {
      int n = q * 4 + jr;
      bvv[jr] = (n < 10) ? b4[n] : 0.f;
    }
    o0 = (f32x4){bvv[0], bvv[1], bvv[2], bvv[3]};
    o1 = o0;
    const u16* w4 = ws + WS_W4 + m * 128 + q * 8;
#pragma unroll
    for (int ks = 0; ks < 4; ++ks) {
      bf16x8 a = *(const bf16x8*)(w4 + ks * 32);
      o0 = __builtin_amdgcn_mfma_f32_16x16x32_bf16(a, bf0[ks], o0, 0, 0, 0);
      o1 = __builtin_amdgcn_mfma_f32_16x16x32_bf16(a, bf1[ks], o1, 0, 0, 0);
    }
  }

  // ---- store: lane (q,m) holds out[row][4q+jr] for its two rows ----
  {
    float* r0 = out + (row0 + (size_t)m) * 10;
    float* r1 = r0 + 16 * 10;
    if (q < 2) {
      *(float2*)(r0 + q * 4)     = make_float2(o0[0], o0[1]);
      *(float2*)(r0 + q * 4 + 2) = make_float2(o0[2], o0[3]);
      *(float2*)(r1 + q * 4)     = make_float2(o1[0], o1[1]);
      *(float2*)(r1 + q * 4 + 2) = make_float2(o1[2], o1[3]);
    } else if (q == 2) {
      *(float2*)(r0 + 8) = make_float2(o0[0], o0[1]);
      *(float2*)(r1 + 8) = make_float2(o1[0], o1[1]);
    }
  }
}

extern "C" void kernel_launch(void* const* d_in, const int* in_sizes, int n_in,
                              void* d_out, int out_size, void* d_ws, size_t ws_size,
                              hipStream_t stream) {
  const float* x  = (const float*)d_in[0];
  const float* W1 = (const float*)d_in[1];
  const float* b1 = (const float*)d_in[2];
  const float* W2 = (const float*)d_in[3];
  const float* b2 = (const float*)d_in[4];
  const float* W3 = (const float*)d_in[5];
  const float* b3 = (const float*)d_in[6];
  const float* W4 = (const float*)d_in[7];
  const float* b4 = (const float*)d_in[8];
  u16* ws = (u16*)d_ws;          // needs 126976 B
  float* out = (float*)d_out;

  prep_kernel<<<248, 256, 0, stream>>>(W1, W2, W3, W4, ws);
  // 524288 rows / 32 rows-per-wave / 4 waves-per-block = 4096 blocks
  mlp_kernel<<<4096, 256, 0, stream>>>(x, ws, b1, b2, b3, b4, out);
}

// Round 2
// 655.183 us; speedup vs baseline: 1.1785x; 1.1785x over previous
//
#include <hip/hip_runtime.h>
#include <cstdint>

// BinaryMLP fused forward for MI355X (gfx950) — register-resident, bt=4.
// h1 = relu(x @ sign(W1)^T + b1); h2 = relu(h1 @ sign(W2)^T + b2);
// h3 = relu(h2 @ sign(W3)^T + b3); out = h3 @ W4^T + b4
// B=524288, D_IN=196 (pad 224), H=128, D_OUT=10 (pad 16).
//
// Swapped-operand MFMA (A = weights, B = batch^T): each lane's D column is
// its own batch row -> h stays lane-local through all layers. k-permutation
// pi baked into prepped W2/W3/W4 makes MFMA D layout == next layer's
// B-fragment layout after in-register relu + v_cvt_pk_bf16_f32.
// No LDS, no barriers. 4 batch sub-tiles per wave (64 rows) so every weight
// a-fragment load feeds 4 MFMAs — halves weight-load instruction rate vs
// bt=2 and doubles per-load ILP. launch_bounds(256,2) opens the VGPR budget
// (round-1's VGPR=72 forced load->mfma serialization).

typedef __attribute__((ext_vector_type(8))) short bf16x8;   // 8 bf16 (4 VGPRs)
typedef __attribute__((ext_vector_type(4))) float f32x4;    // MFMA accumulator

typedef unsigned short u16;
typedef unsigned int u32;

#define BT 4   // batch sub-tiles (16 rows each) per wave

// ws element offsets (bf16 units)
#define WS_W1 0        // [128][224]  straight, zero-padded k>=196
#define WS_W2 28672    // [128][128]  pi-permuted columns
#define WS_W3 45056    // [128][128]  pi-permuted columns
#define WS_W4 61440    // [16][128]   pi-permuted, rows 10..15 zero
#define WS_TOTAL 63488 // 126976 bytes

__device__ __forceinline__ u32 bf16_rne(float x) {
  u32 u = __float_as_uint(x);
  return (u + 0x7FFFu + ((u >> 16) & 1u)) >> 16;
}

__device__ __forceinline__ u16 sign_bf16(float v) {
  return (v > 0.f) ? 0x3F80u : ((v < 0.f) ? 0xBF80u : 0u);
}

// pi: physical position pos -> logical k. Previous layer's D layout (lane
// holds n = 16*mt + 4*q + jr) supplies position pos = 32*ks + 8*q + j with
// mt = 2*ks + (j>>2), jr = j&3 — purely lane-local hand-off.
__device__ __forceinline__ int kperm(int pos) {
  return 32 * (pos >> 5) + 16 * ((pos >> 2) & 1) + 4 * ((pos >> 3) & 3) + (pos & 3);
}

__global__ __launch_bounds__(256) void prep_kernel(
    const float* __restrict__ W1, const float* __restrict__ W2,
    const float* __restrict__ W3, const float* __restrict__ W4,
    u16* __restrict__ ws) {
  int idx = blockIdx.x * 256 + threadIdx.x;   // grid 248 -> 63488 threads exact
  if (idx < WS_W2) {
    int n = idx / 224, k = idx - n * 224;
    ws[idx] = (k < 196) ? sign_bf16(W1[n * 196 + k]) : (u16)0;
  } else if (idx < WS_W3) {
    int j = idx - WS_W2; int n = j >> 7, p = j & 127;
    ws[idx] = sign_bf16(W2[(n << 7) + kperm(p)]);
  } else if (idx < WS_W4) {
    int j = idx - WS_W3; int n = j >> 7, p = j & 127;
    ws[idx] = sign_bf16(W3[(n << 7) + kperm(p)]);
  } else if (idx < WS_TOTAL) {
    int j = idx - WS_W4; int c = j >> 7, p = j & 127;
    ws[idx] = (c < 10) ? (u16)bf16_rne(W4[(c << 7) + kperm(p)]) : (u16)0;
  }
}

union BFU { bf16x8 v; u32 w[4]; };

__device__ __forceinline__ u32 cvtpk(float lo, float hi) {
  u32 r;
  asm("v_cvt_pk_bf16_f32 %0, %1, %2" : "=v"(r) : "v"(lo), "v"(hi));
  return r;
}
__device__ __forceinline__ u32 cvtpk_relu(float lo, float hi) {
  return cvtpk(fmaxf(lo, 0.f), fmaxf(hi, 0.f));
}

// acc tiles (8 per batch sub-tile) -> next layer's 4 B-fragments.
__device__ __forceinline__ void to_bfrag(const f32x4 acc[8], bf16x8 bf[4]) {
#pragma unroll
  for (int ks = 0; ks < 4; ++ks) {
    BFU t;
    t.w[0] = cvtpk_relu(acc[2 * ks][0], acc[2 * ks][1]);
    t.w[1] = cvtpk_relu(acc[2 * ks][2], acc[2 * ks][3]);
    t.w[2] = cvtpk_relu(acc[2 * ks + 1][0], acc[2 * ks + 1][1]);
    t.w[3] = cvtpk_relu(acc[2 * ks + 1][2], acc[2 * ks + 1][3]);
    bf[ks] = t.v;
  }
}

// One K=128 hidden layer: acc[s][mt] = bias; acc += Wp * h^T. Each a-frag
// load feeds BT MFMAs.
__device__ __forceinline__ void layer128(const u16* __restrict__ wp,
                                         const float* __restrict__ bias,
                                         int m, int q,
                                         const bf16x8 bf[BT][4],
                                         f32x4 acc[BT][8]) {
#pragma unroll
  for (int mt = 0; mt < 8; ++mt) {
    f32x4 bv = *(const f32x4*)(bias + mt * 16 + q * 4);
#pragma unroll
    for (int s = 0; s < BT; ++s) acc[s][mt] = bv;
  }
  const u16* wb = wp + m * 128 + q * 8;
#pragma unroll
  for (int ks = 0; ks < 4; ++ks) {
#pragma unroll
    for (int mt = 0; mt < 8; ++mt) {
      bf16x8 a = *(const bf16x8*)(wb + mt * (16 * 128) + ks * 32);
#pragma unroll
      for (int s = 0; s < BT; ++s)
        acc[s][mt] =
            __builtin_amdgcn_mfma_f32_16x16x32_bf16(a, bf[s][ks], acc[s][mt], 0, 0, 0);
    }
  }
}

__global__ __launch_bounds__(256, 2) void mlp_kernel(
    const float* __restrict__ x, const u16* __restrict__ ws,
    const float* __restrict__ b1, const float* __restrict__ b2,
    const float* __restrict__ b3, const float* __restrict__ b4,
    float* __restrict__ out) {
  const int tid = threadIdx.x;
  const int lane = tid & 63;
  const int wave = tid >> 6;
  const int m = lane & 15;   // A row index / batch row within 16
  const int q = lane >> 4;   // k-group: k = 32*ks + 8*q + j
  const size_t row0 = ((size_t)blockIdx.x * 4 + wave) * (16 * BT);

  f32x4 acc[BT][8];

  // ---- Layer 1: h1^T = W1 * x^T, K = 224 (7 k-steps), bias in acc init ----
#pragma unroll
  for (int mt = 0; mt < 8; ++mt) {
    f32x4 bv = *(const f32x4*)(b1 + mt * 16 + q * 4);
#pragma unroll
    for (int s = 0; s < BT; ++s) acc[s][mt] = bv;
  }
  {
    const u16* w1 = ws + WS_W1 + m * 224 + q * 8;
#pragma unroll
    for (int ks = 0; ks < 7; ++ks) {
      BFU xf[BT];
      if (ks < 6) {
#pragma unroll
        for (int s = 0; s < BT; ++s) {
          const float* xr = x + (row0 + (size_t)(s * 16 + m)) * 196 + ks * 32 + q * 8;
          float4 a0 = *(const float4*)(xr);
          float4 a1 = *(const float4*)(xr + 4);
          xf[s].w[0] = cvtpk(a0.x, a0.y); xf[s].w[1] = cvtpk(a0.z, a0.w);
          xf[s].w[2] = cvtpk(a1.x, a1.y); xf[s].w[3] = cvtpk(a1.z, a1.w);
        }
      } else {
        // tail: k = 192..223, only k in [192,196) valid (q==0, j<4)
#pragma unroll
        for (int s = 0; s < BT; ++s) {
          float4 a0 = make_float4(0.f, 0.f, 0.f, 0.f);
          if (q == 0)
            a0 = *(const float4*)(x + (row0 + (size_t)(s * 16 + m)) * 196 + 192);
          xf[s].w[0] = cvtpk(a0.x, a0.y); xf[s].w[1] = cvtpk(a0.z, a0.w);
          xf[s].w[2] = 0u; xf[s].w[3] = 0u;
        }
      }
#pragma unroll
      for (int mt = 0; mt < 8; ++mt) {
        bf16x8 a = *(const bf16x8*)(w1 + mt * (16 * 224) + ks * 32);
#pragma unroll
        for (int s = 0; s < BT; ++s)
          acc[s][mt] =
              __builtin_amdgcn_mfma_f32_16x16x32_bf16(a, xf[s].v, acc[s][mt], 0, 0, 0);
      }
    }
  }

  bf16x8 bf[BT][4];
#pragma unroll
  for (int s = 0; s < BT; ++s) to_bfrag(acc[s], bf[s]);
  layer128(ws + WS_W2, b2, m, q, bf, acc);
#pragma unroll
  for (int s = 0; s < BT; ++s) to_bfrag(acc[s], bf[s]);
  layer128(ws + WS_W3, b3, m, q, bf, acc);
#pragma unroll
  for (int s = 0; s < BT; ++s) to_bfrag(acc[s], bf[s]);

  // ---- Layer 4: out^T = W4p * h3^T (rows 10..15 zero), no relu ----
  f32x4 o[BT];
  {
    float bvv[4];
#pragma unroll
    for (int jr = 0; jr < 4; ++jr) {
      int n = q * 4 + jr;
      bvv[jr] = (n < 10) ? b4[n] : 0.f;
    }
#pragma unroll
    for (int s = 0; s < BT; ++s) o[s] = (f32x4){bvv[0], bvv[1], bvv[2], bvv[3]};
    const u16* w4 = ws + WS_W4 + m * 128 + q * 8;
#pragma unroll
    for (int ks = 0; ks < 4; ++ks) {
      bf16x8 a = *(const bf16x8*)(w4 + ks * 32);
#pragma unroll
      for (int s = 0; s < BT; ++s)
        o[s] = __builtin_amdgcn_mfma_f32_16x16x32_bf16(a, bf[s][ks], o[s], 0, 0, 0);
    }
  }

  // ---- store: lane (q,m) holds out[row][4q+jr] for its BT rows ----
#pragma unroll
  for (int s = 0; s < BT; ++s) {
    float* r = out + (row0 + (size_t)(s * 16 + m)) * 10;
    if (q < 2) {
      *(float2*)(r + q * 4)     = make_float2(o[s][0], o[s][1]);
      *(float2*)(r + q * 4 + 2) = make_float2(o[s][2], o[s][3]);
    } else if (q == 2) {
      *(float2*)(r + 8) = make_float2(o[s][0], o[s][1]);
    }
  }
}

extern "C" void kernel_launch(void* const* d_in, const int* in_sizes, int n_in,
                              void* d_out, int out_size, void* d_ws, size_t ws_size,
                              hipStream_t stream) {
  const float* x  = (const float*)d_in[0];
  const float* W1 = (const float*)d_in[1];
  const float* b1 = (const float*)d_in[2];
  const float* W2 = (const float*)d_in[3];
  const float* b2 = (const float*)d_in[4];
  const float* W3 = (const float*)d_in[5];
  const float* b3 = (const float*)d_in[6];
  const float* W4 = (const float*)d_in[7];
  const float* b4 = (const float*)d_in[8];
  u16* ws = (u16*)d_ws;          // needs 126976 B
  float* out = (float*)d_out;

  prep_kernel<<<248, 256, 0, stream>>>(W1, W2, W3, W4, ws);
  // 524288 rows / (64 rows per wave * 4 waves) = 2048 blocks
  mlp_kernel<<<2048, 256, 0, stream>>>(x, ws, b1, b2, b3, b4, out);
}